// Round 2
// baseline (2746.440 us; speedup 1.0000x reference)
//
#include <hip/hip_runtime.h>
#include <hip/hip_bf16.h>

// ---------------- constants ----------------
#define Nn 4
#define CIN 2048
#define Hh 59
#define Ww 59
#define HW 3481          // 59*59
#define MID 512
#define MM 3481          // mask channels 59*59
#define SH 30
#define SW 30
#define SP 900           // 30*30
#define EPSF 1e-5f

typedef __hip_bfloat16 bf16;

// ---------------- dtype probe: bf16 vs fp32 ----------------
// fp32 data viewed as u16 halfwords: low halves have ~uniform random exponent
// bits -> ~35% land outside [90,160]. True bf16 N(0,1): essentially none.
__global__ void probe_k(const unsigned short* __restrict__ x, int* __restrict__ flag)
{
    __shared__ int cnt;
    if (threadIdx.x == 0) cnt = 0;
    __syncthreads();
    int local = 0;
    for (int i = threadIdx.x; i < 8192; i += 256) {
        unsigned short u = x[i];
        int e = (u >> 7) & 0xFF;
        if (u != 0 && (e < 90 || e > 160)) local++;
    }
    atomicAdd(&cnt, local);
    __syncthreads();
    if (threadIdx.x == 0) *flag = (cnt > 256) ? 1 : 0;   // 1 = fp32
}

__device__ __forceinline__ float load_in(const void* p, long i, int isf32)
{
    return isf32 ? ((const float*)p)[i] : (float)((const bf16*)p)[i];
}

// ---------------- weight convert -> bf16 staging ----------------
__global__ __launch_bounds__(256) void wconv_k(const void* __restrict__ src,
                                               bf16* __restrict__ dst, long n,
                                               const int* __restrict__ flag)
{
    long i = (long)blockIdx.x * 256 + threadIdx.x;
    if (i >= n) return;
    int f = *flag;
    dst[i] = f ? (bf16)((const float*)src)[i] : ((const bf16*)src)[i];
}

// ---------------- BN prep: sb = [scale(C) | bias(C)] fp32 ----------------
__global__ __launch_bounds__(256) void bnprep_k(const void* __restrict__ bnp,
                                                float* __restrict__ sb, int C,
                                                const int* __restrict__ flag)
{
    int c = blockIdx.x * 256 + threadIdx.x;
    if (c >= C) return;
    int f = *flag;
    float g  = load_in(bnp, c, f);
    float b  = load_in(bnp, C + c, f);
    float m  = load_in(bnp, 2 * C + c, f);
    float v  = load_in(bnp, 3 * C + c, f);
    float s = g / sqrtf(v + EPSF);
    sb[c] = s;
    sb[C + c] = b - m * s;
}

// ---------------- subsample x[:, :, ::2, ::2] -> fp32 ----------------
__global__ __launch_bounds__(256) void subsample_k(const void* __restrict__ x,
                                                   float* __restrict__ xs,
                                                   const int* __restrict__ flag)
{
    long idx = (long)blockIdx.x * 256 + threadIdx.x;  // over N*CIN*SP
    int ab = (int)(idx % SP);
    long nc = idx / SP;
    int a = ab / SW, b = ab - a * SW;
    xs[idx] = load_in(x, nc * HW + (long)a * (2 * Ww) + 2 * b, *flag);
}

// ---------------- copy x into out's first-half channels ----------------
__global__ __launch_bounds__(256) void copyx_k(const void* __restrict__ x,
                                               void* __restrict__ out,
                                               const int* __restrict__ flag)
{
    long idx = (long)blockIdx.x * 256 + threadIdx.x;  // over N*CIN*HW
    long per = (long)CIN * HW;
    long n = idx / per;
    long r = idx - n * per;
    long o = n * (2 * per) + r;
    if (*flag) ((float*)out)[o] = ((const float*)x)[idx];
    else       ((bf16*)out)[o]  = ((const bf16*)x)[idx];
}

// ---------------- generic fp32 tiled GEMM ----------------
// Y[z][m][p] = (optional scale/bias+ReLU)( sum_k A[m][k] * X[z][k][p] )
__global__ __launch_bounds__(256) void gemm_k(
    const bf16* __restrict__ Abf, const float* __restrict__ Af, long strideA,
    const float* __restrict__ X, long strideX,
    float* __restrict__ Yf, bf16* __restrict__ Yh, long strideY,
    int M, int K, int Pdim, const float* __restrict__ sb, int relu)
{
    __shared__ float As[16][64];
    __shared__ float Bs[16][64];
    const int z = blockIdx.z;
    const int tid = threadIdx.x;
    const int tx = tid & 15, ty = tid >> 4;
    const int m_base = blockIdx.y * 64;
    const int p_base = blockIdx.x * 64;
    const float* Xb = X + (long)z * strideX;

    float acc[4][4] = {};

    for (int k0 = 0; k0 < K; k0 += 16) {
        {
            int r = tid >> 2;
            int c0 = (tid & 3) * 4;
            int m = m_base + r;
            #pragma unroll
            for (int i = 0; i < 4; i++) {
                int k = k0 + c0 + i;
                float v = 0.f;
                if (m < M && k < K) {
                    long idx = (long)m * K + k + (long)z * strideA;
                    v = Abf ? (float)Abf[idx] : Af[idx];
                }
                As[c0 + i][r] = v;
            }
        }
        {
            int c = tid & 63;
            int r0 = tid >> 6;
            int p = p_base + c;
            #pragma unroll
            for (int i = 0; i < 4; i++) {
                int k = k0 + r0 + i * 4;
                float v = 0.f;
                if (p < Pdim && k < K) v = Xb[(long)k * Pdim + p];
                Bs[r0 + i * 4][c] = v;
            }
        }
        __syncthreads();
        #pragma unroll
        for (int k = 0; k < 16; k++) {
            float a0 = As[k][ty * 4 + 0], a1 = As[k][ty * 4 + 1];
            float a2 = As[k][ty * 4 + 2], a3 = As[k][ty * 4 + 3];
            float b0 = Bs[k][tx * 4 + 0], b1 = Bs[k][tx * 4 + 1];
            float b2 = Bs[k][tx * 4 + 2], b3 = Bs[k][tx * 4 + 3];
            acc[0][0] += a0 * b0; acc[0][1] += a0 * b1; acc[0][2] += a0 * b2; acc[0][3] += a0 * b3;
            acc[1][0] += a1 * b0; acc[1][1] += a1 * b1; acc[1][2] += a1 * b2; acc[1][3] += a1 * b3;
            acc[2][0] += a2 * b0; acc[2][1] += a2 * b1; acc[2][2] += a2 * b2; acc[2][3] += a2 * b3;
            acc[3][0] += a3 * b0; acc[3][1] += a3 * b1; acc[3][2] += a3 * b2; acc[3][3] += a3 * b3;
        }
        __syncthreads();
    }

    long Yoff = (long)z * strideY;
    #pragma unroll
    for (int i = 0; i < 4; i++) {
        int m = m_base + ty * 4 + i;
        if (m >= M) continue;
        float scale = 1.f, bias = 0.f;
        if (sb) { scale = sb[m]; bias = sb[M + m]; }
        #pragma unroll
        for (int j = 0; j < 4; j++) {
            int p = p_base + tx * 4 + j;
            if (p >= Pdim) continue;
            float v = acc[i][j] * scale + bias;
            if (relu) v = fmaxf(v, 0.f);
            long oidx = Yoff + (long)m * Pdim + p;
            if (Yh) Yh[oidx] = (bf16)v;
            else    Yf[oidx] = v;
        }
    }
}

// ---------------- gather + softmax over 900 source positions ----------------
__global__ __launch_bounds__(256) void softmax_gather_k(const bf16* __restrict__ y,
                                                        float* __restrict__ P,
                                                        int collect)
{
    const int ab = blockIdx.x;
    const int n = blockIdx.y;
    const int a = ab / SW, b = ab - a * SW;
    const int t = threadIdx.x;
    __shared__ float red[4];

    float vals[4];
    float mx = -1e30f;
    #pragma unroll
    for (int q = 0; q < 4; q++) {
        int ij = t + q * 256;
        float v = -1e30f;
        if (ij < SP) {
            int i = ij / SW, j = ij - i * SW;
            int m = collect ? (i - a + 29) * 59 + (j - b + 29)
                            : (a - i + 29) * 59 + (b - j + 29);
            int col = collect ? ab : ij;
            v = (float)y[((long)n * MM + m) * SP + col];
        }
        vals[q] = v;
        mx = fmaxf(mx, v);
    }
    #pragma unroll
    for (int off = 32; off; off >>= 1) mx = fmaxf(mx, __shfl_xor(mx, off, 64));
    if ((t & 63) == 0) red[t >> 6] = mx;
    __syncthreads();
    mx = fmaxf(fmaxf(red[0], red[1]), fmaxf(red[2], red[3]));
    __syncthreads();

    float s = 0.f;
    #pragma unroll
    for (int q = 0; q < 4; q++) {
        if (vals[q] > -1e29f) { vals[q] = expf(vals[q] - mx); s += vals[q]; }
        else vals[q] = 0.f;
    }
    #pragma unroll
    for (int off = 32; off; off >>= 1) s += __shfl_xor(s, off, 64);
    if ((t & 63) == 0) red[t >> 6] = s;
    __syncthreads();
    s = red[0] + red[1] + red[2] + red[3];
    float inv = 1.f / s;
    #pragma unroll
    for (int q = 0; q < 4; q++) {
        int ij = t + q * 256;
        if (ij < SP) P[((long)n * SP + ij) * SP + ab] = vals[q] * inv;
    }
}

// ---------------- final 2x upsample (fracs 0 / 0.5), write out 2nd half ------
__global__ __launch_bounds__(256) void upsample_k(const float* __restrict__ xp,
                                                  void* __restrict__ out,
                                                  const int* __restrict__ flag)
{
    long idx = (long)blockIdx.x * 256 + threadIdx.x;  // over N*CIN*HW
    int t = (int)(idx % HW);
    long nc = idx / HW;
    int o = (int)(nc % CIN);
    int n = (int)(nc / CIN);
    int y = t / Ww, xq = t - y * Ww;
    int i = y >> 1, j = xq >> 1;
    const float* bp = xp + nc * SP;
    float v00 = bp[i * SW + j];
    float v;
    bool ye = !(y & 1), xe = !(xq & 1);
    if (ye && xe)      v = v00;
    else if (ye)       v = 0.5f * (v00 + bp[i * SW + j + 1]);
    else if (xe)       v = 0.5f * (v00 + bp[(i + 1) * SW + j]);
    else               v = 0.25f * (v00 + bp[i * SW + j + 1]
                                  + bp[(i + 1) * SW + j] + bp[(i + 1) * SW + j + 1]);
    long oidx = ((long)n * (2 * CIN) + CIN + o) * HW + t;
    if (*flag) ((float*)out)[oidx] = v;
    else       ((bf16*)out)[oidx]  = (bf16)v;
}

// ---------------- launch ----------------
static void launch_gemm(hipStream_t stream,
                        const bf16* Abf, const float* Af, long sA,
                        const float* X, long sX,
                        float* Yf, bf16* Yh, long sY,
                        int M, int K, int P, const float* sb, int relu)
{
    dim3 grid((P + 63) / 64, (M + 63) / 64, Nn);
    hipLaunchKernelGGL(gemm_k, grid, dim3(256), 0, stream,
                       Abf, Af, sA, X, sX, Yf, Yh, sY, M, K, P, sb, relu);
}

extern "C" void kernel_launch(void* const* d_in, const int* in_sizes, int n_in,
                              void* d_out, int out_size, void* d_ws, size_t ws_size,
                              hipStream_t stream)
{
    const void* x    = d_in[0];
    const void* rw   = d_in[1];
    const void* rbn  = d_in[2];
    const void* a1w  = d_in[3];
    const void* abn  = d_in[4];
    const void* a2w  = d_in[5];
    const void* rpw  = d_in[6];
    const void* rpbn = d_in[7];
    const void* ap1w = d_in[8];
    const void* apbn = d_in[9];
    const void* ap2w = d_in[10];
    const void* pjw  = d_in[11];
    const void* pjbn = d_in[12];

    char* W = (char*)d_ws;
    int*  flag  = (int*)(W + 0);
    // bf16 weight staging
    bf16* rw_b   = (bf16*)(W + 1024);
    bf16* rpw_b  = rw_b + 1048576;
    bf16* a1w_b  = rpw_b + 1048576;
    bf16* ap1w_b = a1w_b + 262144;
    bf16* a2w_b  = ap1w_b + 262144;
    bf16* ap2w_b = a2w_b + 1782272;
    bf16* pjw_b  = ap2w_b + 1782272;
    // end = 1024 + 8283136*2 = 16,567,296
    float* rbn_sb  = (float*)(W + 16567296);
    float* abn_sb  = rbn_sb + 1024;
    float* rpbn_sb = abn_sb + 1024;
    float* apbn_sb = rpbn_sb + 1024;
    float* pjbn_sb = apbn_sb + 1024;  // 4096 floats
    // end = 16,567,296 + 32,768 = 16,600,064
    float* x_small = (float*)(W + 16600064);   // 29,491,200  (reused as xp)
    float* xc      = (float*)(W + 46091264);   //  7,372,800
    float* xd      = (float*)(W + 53464064);
    float* h1c     = (float*)(W + 60836864);
    float* h1d     = (float*)(W + 68209664);   // h1c+h1d reused as aggcat
    bf16*  ybuf    = (bf16*)(W + 75582464);    // 25,063,200 (shared c/d)
    float* Pc      = (float*)(W + 100645664);  // 12,960,000
    float* Pd      = (float*)(W + 113605664);  // end 126,565,664
    float* aggcat  = h1c;
    float* xp      = x_small;

    // 1. dtype probe
    hipLaunchKernelGGL(probe_k, dim3(1), dim3(256), 0, stream,
                       (const unsigned short*)x, flag);

    // 2. weight staging (bf16)
    #define WCONV(src, dst, n) hipLaunchKernelGGL(wconv_k, dim3(((n)+255)/256), dim3(256), 0, stream, src, dst, (long)(n), flag)
    WCONV(rw,   rw_b,   1048576);
    WCONV(rpw,  rpw_b,  1048576);
    WCONV(a1w,  a1w_b,  262144);
    WCONV(ap1w, ap1w_b, 262144);
    WCONV(a2w,  a2w_b,  1782272);
    WCONV(ap2w, ap2w_b, 1782272);
    WCONV(pjw,  pjw_b,  2097152);
    #undef WCONV

    // 3. BN prep
    hipLaunchKernelGGL(bnprep_k, dim3(2), dim3(256), 0, stream, rbn,  rbn_sb,  MID, flag);
    hipLaunchKernelGGL(bnprep_k, dim3(2), dim3(256), 0, stream, abn,  abn_sb,  MID, flag);
    hipLaunchKernelGGL(bnprep_k, dim3(2), dim3(256), 0, stream, rpbn, rpbn_sb, MID, flag);
    hipLaunchKernelGGL(bnprep_k, dim3(2), dim3(256), 0, stream, apbn, apbn_sb, MID, flag);
    hipLaunchKernelGGL(bnprep_k, dim3(8), dim3(256), 0, stream, pjbn, pjbn_sb, CIN, flag);

    // 4. subsample + 5. identity copy
    hipLaunchKernelGGL(subsample_k, dim3(28800), dim3(256), 0, stream, x, x_small, flag);
    hipLaunchKernelGGL(copyx_k, dim3(111392), dim3(256), 0, stream, x, d_out, flag);

    const long sXin = (long)CIN * SP;
    const long sMid = (long)MID * SP;
    const long sMM  = (long)MM * SP;
    const long sPP  = (long)SP * SP;
    const long sCat = (long)(2 * MID) * SP;
    const long sPj  = (long)CIN * SP;

    // 6. G1 / G2
    launch_gemm(stream, rw_b,  nullptr, 0, x_small, sXin, xc, nullptr, sMid, MID, CIN, SP, rbn_sb, 1);
    launch_gemm(stream, rpw_b, nullptr, 0, x_small, sXin, xd, nullptr, sMid, MID, CIN, SP, rpbn_sb, 1);
    launch_gemm(stream, a1w_b,  nullptr, 0, xc, sMid, h1c, nullptr, sMid, MID, MID, SP, abn_sb, 1);
    launch_gemm(stream, ap1w_b, nullptr, 0, xd, sMid, h1d, nullptr, sMid, MID, MID, SP, apbn_sb, 1);

    // 7. y + softmax, branch c then d (shared y buffer)
    launch_gemm(stream, a2w_b, nullptr, 0, h1c, sMid, nullptr, ybuf, sMM, MM, MID, SP, nullptr, 0);
    hipLaunchKernelGGL(softmax_gather_k, dim3(SP, Nn), dim3(256), 0, stream, ybuf, Pc, 1);
    launch_gemm(stream, ap2w_b, nullptr, 0, h1d, sMid, nullptr, ybuf, sMM, MM, MID, SP, nullptr, 0);
    hipLaunchKernelGGL(softmax_gather_k, dim3(SP, Nn), dim3(256), 0, stream, ybuf, Pd, 0);

    // 8. aggregation
    launch_gemm(stream, nullptr, xc, sMid, Pc, sPP, aggcat,                  nullptr, sCat, MID, SP, SP, nullptr, 0);
    launch_gemm(stream, nullptr, xd, sMid, Pd, sPP, aggcat + (long)MID * SP, nullptr, sCat, MID, SP, SP, nullptr, 0);

    // 9. projection
    launch_gemm(stream, pjw_b, nullptr, 0, aggcat, sCat, xp, nullptr, sPj, CIN, 2 * MID, SP, pjbn_sb, 1);

    // 10. upsample
    hipLaunchKernelGGL(upsample_k, dim3(111392), dim3(256), 0, stream, xp, d_out, flag);
}

// Round 3
// 727.225 us; speedup vs baseline: 3.7766x; 3.7766x over previous
//
#include <hip/hip_runtime.h>
#include <hip/hip_bf16.h>

#define Nn 4
#define CIN 2048
#define Hh 59
#define Ww 59
#define HW 3481
#define MID 512
#define MMpad 3584       // 3481 padded to mult of 64
#define MMreal 3481
#define SW 30
#define SP 900
#define PP 1024          // pixels padded
#define EPSF 1e-5f

typedef __hip_bfloat16 bf16;
typedef __attribute__((ext_vector_type(8))) short short8;
typedef __attribute__((ext_vector_type(4))) float floatx4;
typedef unsigned short u16;

__device__ __forceinline__ float b2f(u16 u) { return __uint_as_float(((unsigned)u) << 16); }
__device__ __forceinline__ u16 f2b(float f) {
    unsigned u = __float_as_uint(f);
    return (u16)((u + 0x7FFF + ((u >> 16) & 1)) >> 16);  // RNE
}

// ---------------- dtype probe: bf16 vs fp32 ----------------
__global__ void probe_k(const u16* __restrict__ x, int* __restrict__ flag)
{
    __shared__ int cnt;
    if (threadIdx.x == 0) cnt = 0;
    __syncthreads();
    int local = 0;
    for (int i = threadIdx.x; i < 8192; i += 256) {
        u16 u = x[i];
        int e = (u >> 7) & 0xFF;
        if (u != 0 && (e < 90 || e > 160)) local++;
    }
    atomicAdd(&cnt, local);
    __syncthreads();
    if (threadIdx.x == 0) *flag = (cnt > 256) ? 1 : 0;   // 1 = fp32
}

__device__ __forceinline__ float load_in(const void* p, long i, int isf32)
{
    return isf32 ? ((const float*)p)[i] : b2f(((const u16*)p)[i]);
}

// ---------------- weight staging -> bf16 bits ----------------
__global__ __launch_bounds__(256) void wconv_k(const void* __restrict__ src,
                                               u16* __restrict__ dst, long n,
                                               const int* __restrict__ flag)
{
    long i = (long)blockIdx.x * 256 + threadIdx.x;
    if (i >= n) return;
    if (*flag) dst[i] = f2b(((const float*)src)[i]);
    else       dst[i] = ((const u16*)src)[i];
}

// ---------------- BN prep: sb = [scale(C) | bias(C)] fp32 ----------------
__global__ __launch_bounds__(256) void bnprep_k(const void* __restrict__ bnp,
                                                float* __restrict__ sb, int C,
                                                const int* __restrict__ flag)
{
    int c = blockIdx.x * 256 + threadIdx.x;
    if (c >= C) return;
    int f = *flag;
    float g = load_in(bnp, c, f);
    float b = load_in(bnp, C + c, f);
    float m = load_in(bnp, 2 * C + c, f);
    float v = load_in(bnp, 3 * C + c, f);
    float s = g / sqrtf(v + EPSF);
    sb[c] = s;
    sb[C + c] = b - m * s;
}

// ---------------- subsample + transpose: x[n][c][::2,::2] -> xsT[n][p][c] ----
__global__ __launch_bounds__(256) void subsampleT_k(const void* __restrict__ x,
                                                    u16* __restrict__ xsT,
                                                    const int* __restrict__ flag)
{
    __shared__ u16 ls[64][34];
    const int c0 = blockIdx.x * 64;
    const int a  = blockIdx.y;          // 0..29
    const int n  = blockIdx.z;
    const int tid = threadIdx.x;
    const int f = *flag;
    for (int idx = tid; idx < 1920; idx += 256) {
        int ci = idx / 30, b = idx - 30 * (idx / 30);
        float v = load_in(x, ((long)n * CIN + c0 + ci) * HW + a * 118 + 2 * b, f);
        ls[ci][b] = f2b(v);
    }
    __syncthreads();
    for (int idx = tid; idx < 1920; idx += 256) {
        int b = idx >> 6, ci = idx & 63;
        xsT[((long)n * PP + a * 30 + b) * CIN + c0 + ci] = ls[ci][b];
    }
}

// ---------------- identity copy: x -> out first CIN channels ----------------
__global__ __launch_bounds__(256) void copyx_k(const void* __restrict__ x,
                                               void* __restrict__ out,
                                               const int* __restrict__ flag)
{
    long i = (long)blockIdx.x * 256 + threadIdx.x;
    if (*flag) {
        const long per = 1782272;  // uint4 per batch (fp32)
        if (i >= Nn * per) return;
        long n = i / per, r = i - n * per;
        ((uint4*)out)[n * 2 * per + r] = ((const uint4*)x)[i];
    } else {
        const long per = 891136;   // uint4 per batch (bf16)
        if (i >= Nn * per) return;
        long n = i / per, r = i - n * per;
        ((uint4*)out)[n * 2 * per + r] = ((const uint4*)x)[i];
    }
}

// ---------------- MFMA GEMM: C[M=1024/z][N] = A[M][K] * B[N][K]^T ----------
// BM=128, BN=64, BK=32. 256 threads = 4 waves, each 64x32 (4x2 of 16x16).
__device__ __forceinline__ void gl2lds16(const void* g, void* l)
{
    __builtin_amdgcn_global_load_lds(
        (const __attribute__((address_space(1))) void*)g,
        (__attribute__((address_space(3))) void*)l, 16, 0, 0);
}

__global__ __launch_bounds__(256) void mfma_gemm(
    const u16* __restrict__ A, long sA,
    const u16* __restrict__ B, long sB,
    u16* __restrict__ C, long sC, int ldc, int K,
    const float* __restrict__ sb, int sbN, int relu)
{
    __shared__ __align__(16) u16 As[128 * 32];
    __shared__ __align__(16) u16 Bs[64 * 32];
    const int z = blockIdx.z;
    const int tid = threadIdx.x;
    const int lane = tid & 63;
    const int w = tid >> 6;
    const int m_base = blockIdx.y * 128;
    const int n_base = blockIdx.x * 64;
    const u16* Az = A + (long)z * sA;
    const u16* Bz = B + (long)z * sB;

    const int quad = lane >> 4;
    const int l15 = lane & 15;
    const int wr = w >> 1, wc = w & 1;

    const int arow = w * 32 + (lane >> 2);
    const int brow = w * 16 + (lane >> 2);
    const int kcol = (lane & 3) * 8;

    floatx4 acc[4][2] = {};

    for (int k0 = 0; k0 < K; k0 += 32) {
        gl2lds16(Az + (long)(m_base + arow) * K + k0 + kcol,
                 &As[(w * 2 + 0) * 512 + lane * 8]);
        gl2lds16(Az + (long)(m_base + arow + 16) * K + k0 + kcol,
                 &As[(w * 2 + 1) * 512 + lane * 8]);
        gl2lds16(Bz + (long)(n_base + brow) * K + k0 + kcol,
                 &Bs[w * 512 + lane * 8]);
        __syncthreads();
        short8 af[4], bfr[2];
        #pragma unroll
        for (int t = 0; t < 4; t++)
            af[t] = *(const short8*)&As[(wr * 64 + t * 16 + l15) * 32 + quad * 8];
        #pragma unroll
        for (int u = 0; u < 2; u++)
            bfr[u] = *(const short8*)&Bs[(wc * 32 + u * 16 + l15) * 32 + quad * 8];
        #pragma unroll
        for (int t = 0; t < 4; t++)
            #pragma unroll
            for (int u = 0; u < 2; u++)
                acc[t][u] = __builtin_amdgcn_mfma_f32_16x16x32_bf16(af[t], bfr[u], acc[t][u], 0, 0, 0);
        __syncthreads();
    }

    long Cz = (long)z * sC;
    #pragma unroll
    for (int u = 0; u < 2; u++) {
        int n = n_base + wc * 32 + u * 16 + l15;
        float scale = 1.f, bias = 0.f;
        if (sb) { scale = sb[n]; bias = sb[sbN + n]; }
        #pragma unroll
        for (int t = 0; t < 4; t++) {
            int mrow = m_base + wr * 64 + t * 16 + quad * 4;
            #pragma unroll
            for (int r = 0; r < 4; r++) {
                float v = acc[t][u][r];
                if (sb) v = v * scale + bias;
                if (relu) v = fmaxf(v, 0.f);
                C[Cz + (long)(mrow + r) * ldc + n] = f2b(v);
            }
        }
    }
}

// ---------------- batched 64x64 tiled transpose (bf16 bits) ----------------
__global__ __launch_bounds__(256) void transpose64_k(const u16* __restrict__ in,
                                                     u16* __restrict__ out,
                                                     int R, int Cc, long sIn, long sOut)
{
    __shared__ u16 ls[64][66];
    const int c0 = blockIdx.x * 64;
    const int r0 = blockIdx.y * 64;
    const int z = blockIdx.z;
    const int tid = threadIdx.x;
    const int t63 = tid & 63, t2 = tid >> 6;
    #pragma unroll
    for (int s = 0; s < 16; s++) {
        int rl = t2 + s * 4;
        ls[rl][t63] = in[(long)z * sIn + (long)(r0 + rl) * Cc + c0 + t63];
    }
    __syncthreads();
    #pragma unroll
    for (int s = 0; s < 16; s++) {
        int cl = t2 + s * 4;
        out[(long)z * sOut + (long)(c0 + cl) * R + r0 + t63] = ls[t63][cl];
    }
}

// ---------------- gather + softmax: y_t[n][p][m3584] -> P_t[n][ab][ij] -----
__global__ __launch_bounds__(256) void softmax_gather_k(const u16* __restrict__ y,
                                                        u16* __restrict__ P,
                                                        int collect)
{
    const int ab = blockIdx.x;      // 0..899
    const int n = blockIdx.y;
    const int a = ab / SW, b = ab - a * SW;
    const int t = threadIdx.x;
    __shared__ float red[4];

    float vals[4];
    float mx = -1e30f;
    #pragma unroll
    for (int q = 0; q < 4; q++) {
        int ij = t + q * 256;
        float v = -1e30f;
        if (ij < SP) {
            int i = ij / SW, j = ij - (ij / SW) * SW;
            long idx;
            if (collect) idx = ((long)n * PP + ab) * MMpad + (i - a + 29) * 59 + (j - b + 29);
            else         idx = ((long)n * PP + ij) * MMpad + (a - i + 29) * 59 + (b - j + 29);
            v = b2f(y[idx]);
        }
        vals[q] = v;
        mx = fmaxf(mx, v);
    }
    #pragma unroll
    for (int off = 32; off; off >>= 1) mx = fmaxf(mx, __shfl_xor(mx, off, 64));
    if ((t & 63) == 0) red[t >> 6] = mx;
    __syncthreads();
    mx = fmaxf(fmaxf(red[0], red[1]), fmaxf(red[2], red[3]));
    __syncthreads();

    float s = 0.f;
    #pragma unroll
    for (int q = 0; q < 4; q++) {
        if (vals[q] > -1e29f) { vals[q] = expf(vals[q] - mx); s += vals[q]; }
        else vals[q] = 0.f;
    }
    #pragma unroll
    for (int off = 32; off; off >>= 1) s += __shfl_xor(s, off, 64);
    if ((t & 63) == 0) red[t >> 6] = s;
    __syncthreads();
    s = red[0] + red[1] + red[2] + red[3];
    float inv = 1.f / s;
    #pragma unroll
    for (int q = 0; q < 4; q++) {
        int ij = t + q * 256;
        if (ij < SP) P[((long)n * PP + ab) * PP + ij] = f2b(vals[q] * inv);
    }
}

// ---------------- 2x upsample from xp_t[n][p][c], write out 2nd half --------
__global__ __launch_bounds__(256) void upsample_k(const u16* __restrict__ xp,
                                                  void* __restrict__ out,
                                                  const int* __restrict__ flag)
{
    __shared__ u16 ls[2][30][66];
    const int o0 = blockIdx.x * 64;
    const int y  = blockIdx.y;          // 0..58
    const int n  = blockIdx.z;
    const int tid = threadIdx.x;
    const int i = y >> 1;
    const int i1 = (i + 1 < 30) ? i + 1 : 29;
    const int c = tid & 63;
    for (int row = tid >> 6; row < 60; row += 4) {
        int r = row / 30, j = row - 30 * (row / 30);
        int pr = (r == 0) ? i : i1;
        ls[r][j][c] = xp[((long)n * PP + pr * 30 + j) * CIN + o0 + c];
    }
    __syncthreads();
    const int xcol = tid & 63;
    const int oi = tid >> 6;
    if (xcol < 59) {
        int j = xcol >> 1;
        bool xe = !(xcol & 1), ye = !(y & 1);
        int f = *flag;
        for (int oo = oi; oo < 64; oo += 4) {
            float v00 = b2f(ls[0][j][oo]);
            float v;
            if (ye && xe)      v = v00;
            else if (ye)       v = 0.5f * (v00 + b2f(ls[0][j + 1][oo]));
            else if (xe)       v = 0.5f * (v00 + b2f(ls[1][j][oo]));
            else               v = 0.25f * (v00 + b2f(ls[0][j + 1][oo])
                                          + b2f(ls[1][j][oo]) + b2f(ls[1][j + 1][oo]));
            long oidx = ((long)n * (2 * CIN) + CIN + o0 + oo) * HW + (long)y * 59 + xcol;
            if (f) ((float*)out)[oidx] = v;
            else   ((u16*)out)[oidx] = f2b(v);
        }
    }
}

// ---------------- launch ----------------
extern "C" void kernel_launch(void* const* d_in, const int* in_sizes, int n_in,
                              void* d_out, int out_size, void* d_ws, size_t ws_size,
                              hipStream_t stream)
{
    const void* x    = d_in[0];
    const void* rw   = d_in[1];
    const void* rbn  = d_in[2];
    const void* a1w  = d_in[3];
    const void* abn  = d_in[4];
    const void* a2w  = d_in[5];
    const void* rpw  = d_in[6];
    const void* rpbn = d_in[7];
    const void* ap1w = d_in[8];
    const void* apbn = d_in[9];
    const void* ap2w = d_in[10];
    const void* pjw  = d_in[11];
    const void* pjbn = d_in[12];

    char* W = (char*)d_ws;
    int* flag    = (int*)(W + 0);
    u16* rw_b    = (u16*)(W + 1024);          // 512x2048
    u16* rpw_b   = (u16*)(W + 2098176);       // 512x2048
    u16* a1w_b   = (u16*)(W + 4195328);       // 512x512
    u16* ap1w_b  = (u16*)(W + 4719616);       // 512x512
    u16* a2w_b   = (u16*)(W + 5243904);       // 3584x512 (pad rows garbage)
    u16* ap2w_b  = (u16*)(W + 8913920);       // 3584x512
    u16* pjw_b   = (u16*)(W + 12583936);      // 2048x1024
    float* rbn_sb  = (float*)(W + 16778240);
    float* abn_sb  = (float*)(W + 16782336);
    float* rpbn_sb = (float*)(W + 16786432);
    float* apbn_sb = (float*)(W + 16790528);
    float* pjbn_sb = (float*)(W + 16794624);  // 16KB
    u16* x_small_t = (u16*)(W + 16811264);    // 4x1024x2048 (reused as xp_t)
    u16* xc_t      = (u16*)(W + 33588480);    // 4x1024x512
    u16* xd_t      = (u16*)(W + 37782784);
    u16* xc_o      = (u16*)(W + 41977088);    // 4x512x1024
    u16* xd_o      = (u16*)(W + 46171392);
    u16* h1_t      = (u16*)(W + 50365696);    // 4x1024x512 (shared c/d)
    u16* y_t       = (u16*)(W + 54560000);    // 4x1024x3584 (shared c/d)
    u16* Pc        = (u16*)(W + 83920128);    // 4x1024x1024
    u16* Pd        = (u16*)(W + 92308736);
    u16* cat_t     = (u16*)(W + 100697344);   // 4x1024x1024
    u16* xp_t      = x_small_t;

    // zero P (k-padding must be exact zero for agg GEMM)
    hipMemsetAsync(Pc, 0, 16777216, stream);

    hipLaunchKernelGGL(probe_k, dim3(1), dim3(256), 0, stream, (const u16*)x, flag);

    #define WCONV(src, dst, n) hipLaunchKernelGGL(wconv_k, dim3((unsigned)(((n)+255)/256)), dim3(256), 0, stream, src, dst, (long)(n), flag)
    WCONV(rw,   rw_b,   1048576);
    WCONV(rpw,  rpw_b,  1048576);
    WCONV(a1w,  a1w_b,  262144);
    WCONV(ap1w, ap1w_b, 262144);
    WCONV(a2w,  a2w_b,  1782272);
    WCONV(ap2w, ap2w_b, 1782272);
    WCONV(pjw,  pjw_b,  2097152);
    #undef WCONV

    hipLaunchKernelGGL(bnprep_k, dim3(2), dim3(256), 0, stream, rbn,  rbn_sb,  MID, flag);
    hipLaunchKernelGGL(bnprep_k, dim3(2), dim3(256), 0, stream, abn,  abn_sb,  MID, flag);
    hipLaunchKernelGGL(bnprep_k, dim3(2), dim3(256), 0, stream, rpbn, rpbn_sb, MID, flag);
    hipLaunchKernelGGL(bnprep_k, dim3(2), dim3(256), 0, stream, apbn, apbn_sb, MID, flag);
    hipLaunchKernelGGL(bnprep_k, dim3(8), dim3(256), 0, stream, pjbn, pjbn_sb, CIN, flag);

    hipLaunchKernelGGL(subsampleT_k, dim3(32, 30, 4), dim3(256), 0, stream, x, x_small_t, flag);
    hipLaunchKernelGGL(copyx_k, dim3(27848), dim3(256), 0, stream, x, d_out, flag);

    const long sXin = (long)PP * CIN;
    const long sMid = (long)PP * MID;
    const long sMM  = (long)PP * MMpad;
    const long sO   = (long)MID * PP;
    const long sPPl = (long)PP * PP;

    // G1: xc_t = relu(bn(x_small_t @ rw^T))
    hipLaunchKernelGGL(mfma_gemm, dim3(8, 8, 4), dim3(256), 0, stream,
                       x_small_t, sXin, rw_b, 0L, xc_t, sMid, MID, CIN, rbn_sb, MID, 1);
    hipLaunchKernelGGL(mfma_gemm, dim3(8, 8, 4), dim3(256), 0, stream,
                       x_small_t, sXin, rpw_b, 0L, xd_t, sMid, MID, CIN, rpbn_sb, MID, 1);
    // transposes for agg B operands
    hipLaunchKernelGGL(transpose64_k, dim3(8, 16, 4), dim3(256), 0, stream,
                       xc_t, xc_o, PP, MID, sMid, sO);
    hipLaunchKernelGGL(transpose64_k, dim3(8, 16, 4), dim3(256), 0, stream,
                       xd_t, xd_o, PP, MID, sMid, sO);
    // branch c: G2, G3, softmax
    hipLaunchKernelGGL(mfma_gemm, dim3(8, 8, 4), dim3(256), 0, stream,
                       xc_t, sMid, a1w_b, 0L, h1_t, sMid, MID, MID, abn_sb, MID, 1);
    hipLaunchKernelGGL(mfma_gemm, dim3(56, 8, 4), dim3(256), 0, stream,
                       h1_t, sMid, a2w_b, 0L, y_t, sMM, MMpad, MID, (const float*)nullptr, 0, 0);
    hipLaunchKernelGGL(softmax_gather_k, dim3(900, 4), dim3(256), 0, stream, y_t, Pc, 1);
    // branch d
    hipLaunchKernelGGL(mfma_gemm, dim3(8, 8, 4), dim3(256), 0, stream,
                       xd_t, sMid, ap1w_b, 0L, h1_t, sMid, MID, MID, apbn_sb, MID, 1);
    hipLaunchKernelGGL(mfma_gemm, dim3(56, 8, 4), dim3(256), 0, stream,
                       h1_t, sMid, ap2w_b, 0L, y_t, sMM, MMpad, MID, (const float*)nullptr, 0, 0);
    hipLaunchKernelGGL(softmax_gather_k, dim3(900, 4), dim3(256), 0, stream, y_t, Pd, 0);
    // agg: cat_t[:, :512] = Pc @ xc_o^T ; cat_t[:, 512:] = Pd @ xd_o^T
    hipLaunchKernelGGL(mfma_gemm, dim3(8, 8, 4), dim3(256), 0, stream,
                       Pc, sPPl, xc_o, sO, cat_t, sPPl, PP, PP, (const float*)nullptr, 0, 0);
    hipLaunchKernelGGL(mfma_gemm, dim3(8, 8, 4), dim3(256), 0, stream,
                       Pd, sPPl, xd_o, sO, cat_t + 512, sPPl, PP, PP, (const float*)nullptr, 0, 0);
    // projection: xp_t = relu(bn(cat_t @ pjw^T))
    hipLaunchKernelGGL(mfma_gemm, dim3(32, 8, 4), dim3(256), 0, stream,
                       cat_t, sPPl, pjw_b, 0L, xp_t, sXin, CIN, PP, pjbn_sb, CIN, 1);
    // upsample
    hipLaunchKernelGGL(upsample_k, dim3(32, 59, 4), dim3(256), 0, stream, xp_t, d_out, flag);
}